// Round 13
// baseline (325.598 us; speedup 1.0000x reference)
//
#include <hip/hip_runtime.h>
#include <hip/hip_fp16.h>

#define D 128
#define HB 128        // histogram blocks per role (edge-partitioned)
#define HT 1024       // threads per histogram block
#define WMAX 12800    // LDS histogram words (4 nodes/word, byte counters)

struct alignas(16) H8 { __half2 h[4]; };
typedef _Float16 v8h __attribute__((ext_vector_type(8)));
typedef float v4f __attribute__((ext_vector_type(4)));

// ---------------------------------------------------------------------------
// Edge-partitioned LDS histogram (R8-proven) + merged W-prep role.
// ---------------------------------------------------------------------------
__global__ __launch_bounds__(HT) void hist_kernel(const int* __restrict__ src,
                                                  const int* __restrict__ dst,
                                                  unsigned* __restrict__ partial_out,
                                                  unsigned* __restrict__ partial_in,
                                                  unsigned char* __restrict__ lrank,
                                                  const float* __restrict__ W1,
                                                  const float* __restrict__ W2,
                                                  const float* __restrict__ W3,
                                                  _Float16* __restrict__ wt,
                                                  int nE, int W, int epb) {
    const int t = threadIdx.x;
    if ((int)blockIdx.x >= 2 * HB) {                 // W-prep role
        const int l = blockIdx.x - 2 * HB;
        const float* Wsrc = (l == 0) ? W1 : ((l == 1) ? W2 : W3);
        _Float16* o = wt + (size_t)l * D * D;
        for (int i = t; i < D * D; i += HT) {
            const int k = i >> 7, n = i & 127;
            o[n * D + k] = (_Float16)Wsrc[i];
        }
        return;
    }
    __shared__ unsigned lcnt[WMAX];
    const bool is_dst = (blockIdx.x < HB);
    const int b = is_dst ? blockIdx.x : (blockIdx.x - HB);
    for (int i = t; i < W; i += HT) lcnt[i] = 0;
    __syncthreads();
    const int e0 = b * epb;
    const int e1 = min(nE, e0 + epb);
    if (is_dst) {
        for (int e = e0 + t; e < e1; e += HT) {
            const int d = dst[e];
            const unsigned sh = (unsigned)(d & 3) * 8u;
            const unsigned old = atomicAdd(&lcnt[d >> 2], 1u << sh);
            lrank[e] = (unsigned char)((old >> sh) & 0xffu);
        }
    } else {
        for (int e = e0 + t; e < e1; e += HT) {
            const int s = src[e];
            atomicAdd(&lcnt[s >> 2], 1u << ((unsigned)(s & 3) * 8u));
        }
    }
    __syncthreads();
    unsigned* g = (is_dst ? partial_in : partial_out) + (size_t)b * W;
    for (int i = t; i < W; i += HT) g[i] = lcnt[i];
}

// ---------------------------------------------------------------------------
// Reduce 128 partials per node-word (byte-parallel; totals < 256).
// ---------------------------------------------------------------------------
__global__ __launch_bounds__(256) void reduce_hist_kernel(const unsigned* __restrict__ partial_out,
                                                          const unsigned* __restrict__ partial_in,
                                                          unsigned* __restrict__ offs_in,
                                                          int* __restrict__ cnt_out,
                                                          int* __restrict__ cnt_in,
                                                          int W, int n, int nbW) {
    const bool is_dst = ((int)blockIdx.x < nbW);
    const int w = (is_dst ? blockIdx.x : (blockIdx.x - nbW)) * 256 + threadIdx.x;
    if (w >= W) return;
    unsigned run = 0;
    if (is_dst) {
#pragma unroll 16
        for (int b = 0; b < HB; ++b) {
            const unsigned c = partial_in[(size_t)b * W + w];
            offs_in[(size_t)b * W + w] = run;
            run += c;
        }
    } else {
#pragma unroll 16
        for (int b = 0; b < HB; ++b) run += partial_out[(size_t)b * W + w];
    }
    int* cnt = is_dst ? cnt_in : cnt_out;
    const int n0 = w * 4;
    const int4 c4 = make_int4((int)(run & 0xffu), (int)((run >> 8) & 0xffu),
                              (int)((run >> 16) & 0xffu), (int)((run >> 24) & 0xffu));
    if (n0 + 3 < n) {
        *(int4*)&cnt[n0] = c4;
    } else {
        const int* cp = &c4.x;
        for (int i = 0; i < 4 && n0 + i < n; ++i) cnt[n0 + i] = cp[i];
    }
}

// ---------------------------------------------------------------------------
// Exclusive scan stage 1.
// ---------------------------------------------------------------------------
__global__ __launch_bounds__(1024) void scan_block_kernel(const int* __restrict__ deg,
                                                          int* __restrict__ rp,
                                                          int* __restrict__ bsum, int n) {
    __shared__ int wsum[16];
    const int t = threadIdx.x;
    const int lane = t & 63;
    const int wid = t >> 6;
    const int i = blockIdx.x * 1024 + t;
    const int v = (i < n) ? deg[i] : 0;
    int s = v;
#pragma unroll
    for (int off = 1; off < 64; off <<= 1) {
        int u = __shfl_up(s, off, 64);
        if (lane >= off) s += u;
    }
    if (lane == 63) wsum[wid] = s;
    __syncthreads();
    if (wid == 0) {
        int ws = (lane < 16) ? wsum[lane] : 0;
#pragma unroll
        for (int off = 1; off < 16; off <<= 1) {
            int u = __shfl_up(ws, off, 64);
            if (lane >= off) ws += u;
        }
        if (lane < 16) wsum[lane] = ws;
    }
    __syncthreads();
    const int excl = s - v + ((wid > 0) ? wsum[wid - 1] : 0);
    if (i < n) rp[i] = excl;
    if (t == 0) bsum[blockIdx.x] = wsum[15];
}

// ---------------------------------------------------------------------------
// Stage 2 fused with norms; rp[n]=E known a priori.
// ---------------------------------------------------------------------------
__global__ __launch_bounds__(1024) void finalize_kernel(int* __restrict__ rp,
                                                        const int* __restrict__ bsum,
                                                        const int* __restrict__ cnt_out,
                                                        const int* __restrict__ cnt_in,
                                                        float* __restrict__ onorm,
                                                        float* __restrict__ inorm,
                                                        int n, int nb, int nE) {
    __shared__ int prefix_s;
    const int t = threadIdx.x;
    if (t < 64) {
        int v = (t < nb && t < (int)blockIdx.x) ? bsum[t] : 0;
#pragma unroll
        for (int off = 1; off < 64; off <<= 1) v += __shfl_xor(v, off, 64);
        if (t == 0) prefix_s = v;
    }
    __syncthreads();
    const int i = blockIdx.x * 1024 + t;
    if (i < n) {
        rp[i] += prefix_s;
        onorm[i] = rsqrtf(fmaxf((float)cnt_out[i], 1.0f));
        inorm[i] = rsqrtf(fmaxf((float)cnt_in[i], 1.0f));
    }
    if (blockIdx.x == 0 && t == 0) rp[n] = nE;
}

// ---------------------------------------------------------------------------
// FUSED: GEMM1 (y1 = (x@W1)*onorm -> fp16, MFMA) + atomic-free CSR fill
// (R12-proven: independent work, disjoint resources).
// ---------------------------------------------------------------------------
__global__ __launch_bounds__(1024) void gemm1_fill_kernel(
    const float* __restrict__ x, const _Float16* __restrict__ wt,
    const float* __restrict__ onorm, __half* __restrict__ y1, int nrows,
    const int* __restrict__ src, const int* __restrict__ dst,
    const unsigned char* __restrict__ lrank, const unsigned* __restrict__ offs_in,
    const int* __restrict__ rp, int* __restrict__ srcs_sorted,
    int nE, int epb, int W, int nGemmBlocks) {
    __shared__ _Float16 sA[128 * 136];
    __shared__ _Float16 sB[128 * 136];
    const int t = threadIdx.x;

    if ((int)blockIdx.x >= nGemmBlocks) {
        const int e = (blockIdx.x - nGemmBlocks) * 1024 + t;
        if (e < nE) {
            const int d = dst[e];
            const int b = e / epb;
            const unsigned off =
                (offs_in[(size_t)b * W + (d >> 2)] >> ((unsigned)(d & 3) * 8u)) & 0xffu;
            srcs_sorted[rp[d] + (int)off + (int)lrank[e]] = src[e];
        }
        return;
    }

    const int row0 = blockIdx.x * 128;
    const int rr = t >> 4;
    const int c8 = t & 15;
#pragma unroll
    for (int pass = 0; pass < 2; ++pass) {
        const int row = pass * 64 + rr;
        *(float4*)&sB[row * 136 + c8 * 8] = *(const float4*)&wt[(size_t)row * D + c8 * 8];
        const int grow = row0 + row;
        float4 u0 = make_float4(0.f, 0.f, 0.f, 0.f);
        float4 u1 = u0;
        if (grow < nrows) {
            const float* ap = x + (size_t)grow * D + c8 * 8;
            u0 = ((const float4*)ap)[0];
            u1 = ((const float4*)ap)[1];
        }
        v8h hv;
        hv[0] = (_Float16)u0.x; hv[1] = (_Float16)u0.y;
        hv[2] = (_Float16)u0.z; hv[3] = (_Float16)u0.w;
        hv[4] = (_Float16)u1.x; hv[5] = (_Float16)u1.y;
        hv[6] = (_Float16)u1.z; hv[7] = (_Float16)u1.w;
        *(v8h*)&sA[row * 136 + c8 * 8] = hv;
    }
    __syncthreads();

    const int w = t >> 6;
    const int lane = t & 63;
    const int m16 = lane & 15;
    const int quad = lane >> 4;
    const int rt = w >> 1;
    const int ch = w & 1;

    v4f c[4];
#pragma unroll
    for (int ct = 0; ct < 4; ++ct) c[ct] = (v4f){0.f, 0.f, 0.f, 0.f};

#pragma unroll
    for (int ks = 0; ks < 4; ++ks) {
        const v8h a = *(const v8h*)&sA[(rt * 16 + m16) * 136 + ks * 32 + quad * 8];
#pragma unroll
        for (int ct = 0; ct < 4; ++ct) {
            const v8h b = *(const v8h*)&sB[((ch * 4 + ct) * 16 + m16) * 136 + ks * 32 + quad * 8];
            c[ct] = __builtin_amdgcn_mfma_f32_16x16x32_f16(a, b, c[ct], 0, 0, 0);
        }
    }

#pragma unroll
    for (int r = 0; r < 4; ++r) {
        const int row = row0 + rt * 16 + quad * 4 + r;
        if (row < nrows) {
            const float osc = onorm[row];
#pragma unroll
            for (int ct = 0; ct < 4; ++ct) {
                const int col = (ch * 4 + ct) * 16 + m16;
                y1[(size_t)row * D + col] = __float2half(c[ct][r] * osc);
            }
        }
    }
}

// ---------------------------------------------------------------------------
// Standalone aggregate for layer 1 (wave-per-node, R11 wide gather layout).
// EPI: out = relu(r*inorm+b)*onorm -> fp16.
// ---------------------------------------------------------------------------
__global__ __launch_bounds__(256) void aggregate_kernel(const __half* __restrict__ xh,
                                                        const float* __restrict__ onorm,
                                                        const float* __restrict__ inorm,
                                                        const float* __restrict__ bias,
                                                        const int* __restrict__ rp,
                                                        const int* __restrict__ srcs,
                                                        __half* __restrict__ agg, int n_nodes) {
    const int node = blockIdx.x * 4 + (threadIdx.x >> 6);
    const int lane = threadIdx.x & 63;
    const int rg = lane >> 4;
    const int c8 = lane & 15;
    if (node >= n_nodes) return;
    const int e0 = rp[node];
    const int e1 = rp[node + 1];

    float acc0[8], acc1[8];
#pragma unroll
    for (int j = 0; j < 8; ++j) { acc0[j] = 0.f; acc1[j] = 0.f; }

    auto accum = [&](float* acc, const H8 v) {
#pragma unroll
        for (int j = 0; j < 4; ++j) {
            acc[2 * j]     += __low2float(v.h[j]);
            acc[2 * j + 1] += __high2float(v.h[j]);
        }
    };

    int e = e0;
    for (; e + 16 <= e1; e += 16) {
        const int s0 = srcs[e + rg];
        const int s1 = srcs[e + 4 + rg];
        const int s2 = srcs[e + 8 + rg];
        const int s3 = srcs[e + 12 + rg];
        const H8 v0 = ((const H8*)(xh + (size_t)s0 * D))[c8];
        const H8 v1 = ((const H8*)(xh + (size_t)s1 * D))[c8];
        const H8 v2 = ((const H8*)(xh + (size_t)s2 * D))[c8];
        const H8 v3 = ((const H8*)(xh + (size_t)s3 * D))[c8];
        accum(acc0, v0); accum(acc1, v1); accum(acc0, v2); accum(acc1, v3);
    }
    for (; e + 4 <= e1; e += 4) {
        const int s0 = srcs[e + rg];
        accum(acc0, ((const H8*)(xh + (size_t)s0 * D))[c8]);
    }
    if (e < e1 && rg < (e1 - e)) {
        const int s0 = srcs[e + rg];
        accum(acc1, ((const H8*)(xh + (size_t)s0 * D))[c8]);
    }

    float r[8];
#pragma unroll
    for (int j = 0; j < 8; ++j) r[j] = acc0[j] + acc1[j];
#pragma unroll
    for (int off = 16; off < 64; off <<= 1)
#pragma unroll
        for (int j = 0; j < 8; ++j) r[j] += __shfl_xor(r[j], off, 64);

    if (rg == 0) {
        const float inm = inorm[node];
        const float onm = onorm[node];
        const float4 bv0 = ((const float4*)bias)[c8 * 2];
        const float4 bv1 = ((const float4*)bias)[c8 * 2 + 1];
        const float* bp0 = &bv0.x;
        const float* bp1 = &bv1.x;
#pragma unroll
        for (int j = 0; j < 4; ++j) {
            r[j]     = fmaxf(fmaf(r[j],     inm, bp0[j]), 0.f) * onm;
            r[j + 4] = fmaxf(fmaf(r[j + 4], inm, bp1[j]), 0.f) * onm;
        }
        H8 h;
#pragma unroll
        for (int j = 0; j < 4; ++j) h.h[j] = __floats2half2_rn(r[2 * j], r[2 * j + 1]);
        ((H8*)(agg + (size_t)node * D))[c8] = h;
    }
}

// ---------------------------------------------------------------------------
// FUSED aggregate -> MFMA GEMM (layers 2/3): eliminates the 12.8MB a-buffer
// round trip per layer. Block = 64-node tile, 4 waves:
//  phase 1: stage Wt in sB; each wave gathers 16 nodes (R11 wide layout) and
//           writes the fp16 row directly into sA (same quantization point as
//           the old global a-buffer);
//  phase 2: 64x128 MFMA tile, epilogue.
// LDS 52KB -> 3 blocks/CU; 782 blocks; tile degree-sum sigma ~2% -> balanced.
// LAST=false (layer2): out = relu(v*inorm+b)*onorm -> fp16.
// LAST=true  (layer3): out = v*inorm+b -> fp32 d_out.
// ---------------------------------------------------------------------------
template <bool LAST>
__global__ __launch_bounds__(256) void agg_gemm_kernel(const __half* __restrict__ xh,
                                                       const _Float16* __restrict__ Wt,
                                                       const float* __restrict__ bias,
                                                       const float* __restrict__ inorm,
                                                       const float* __restrict__ onorm,
                                                       const int* __restrict__ rp,
                                                       const int* __restrict__ srcs,
                                                       void* __restrict__ outv, int n_nodes) {
    __shared__ _Float16 sA[64 * 136];    // 17.4 KB
    __shared__ _Float16 sB[128 * 136];   // 34.8 KB
    const int t = threadIdx.x;
    const int tile0 = blockIdx.x * 64;

    // Stage Wt (streaming, L2-hot after first blocks)
    {
        const int rr = t >> 4;
        const int cc = t & 15;
#pragma unroll
        for (int p = 0; p < 8; ++p) {
            const int row = p * 16 + rr;
            *(float4*)&sB[row * 136 + cc * 8] = *(const float4*)&Wt[(size_t)row * D + cc * 8];
        }
    }

    const int w = t >> 6;
    const int lane = t & 63;
    const int rg = lane >> 4;
    const int c8 = lane & 15;

    // Phase 1: gather 16 nodes per wave into sA
    for (int i = 0; i < 16; ++i) {
        const int lrow = w * 16 + i;
        const int node = tile0 + lrow;
        float r[8];
#pragma unroll
        for (int j = 0; j < 8; ++j) r[j] = 0.f;
        if (node < n_nodes) {
            const int e0 = rp[node];
            const int e1 = rp[node + 1];
            float acc1[8];
#pragma unroll
            for (int j = 0; j < 8; ++j) acc1[j] = 0.f;
            auto accum = [&](float* acc, const H8 v) {
#pragma unroll
                for (int j = 0; j < 4; ++j) {
                    acc[2 * j]     += __low2float(v.h[j]);
                    acc[2 * j + 1] += __high2float(v.h[j]);
                }
            };
            int e = e0;
            for (; e + 16 <= e1; e += 16) {
                const int s0 = srcs[e + rg];
                const int s1 = srcs[e + 4 + rg];
                const int s2 = srcs[e + 8 + rg];
                const int s3 = srcs[e + 12 + rg];
                const H8 v0 = ((const H8*)(xh + (size_t)s0 * D))[c8];
                const H8 v1 = ((const H8*)(xh + (size_t)s1 * D))[c8];
                const H8 v2 = ((const H8*)(xh + (size_t)s2 * D))[c8];
                const H8 v3 = ((const H8*)(xh + (size_t)s3 * D))[c8];
                accum(r, v0); accum(acc1, v1); accum(r, v2); accum(acc1, v3);
            }
            for (; e + 4 <= e1; e += 4) {
                const int s0 = srcs[e + rg];
                accum(r, ((const H8*)(xh + (size_t)s0 * D))[c8]);
            }
            if (e < e1 && rg < (e1 - e)) {
                const int s0 = srcs[e + rg];
                accum(acc1, ((const H8*)(xh + (size_t)s0 * D))[c8]);
            }
#pragma unroll
            for (int j = 0; j < 8; ++j) r[j] += acc1[j];
#pragma unroll
            for (int off = 16; off < 64; off <<= 1)
#pragma unroll
                for (int j = 0; j < 8; ++j) r[j] += __shfl_xor(r[j], off, 64);
        }
        if (rg == 0) {
            H8 h;
#pragma unroll
            for (int j = 0; j < 4; ++j) h.h[j] = __floats2half2_rn(r[2 * j], r[2 * j + 1]);
            *(H8*)&sA[lrow * 136 + c8 * 8] = h;
        }
    }
    __syncthreads();

    // Phase 2: 64x128 MFMA tile (wave = 16-row tile x all 128 cols)
    const int m16 = lane & 15;
    const int quad = lane >> 4;
    v4f c[8];
#pragma unroll
    for (int ct = 0; ct < 8; ++ct) c[ct] = (v4f){0.f, 0.f, 0.f, 0.f};

#pragma unroll
    for (int ks = 0; ks < 4; ++ks) {
        const v8h a = *(const v8h*)&sA[(w * 16 + m16) * 136 + ks * 32 + quad * 8];
#pragma unroll
        for (int ct = 0; ct < 8; ++ct) {
            const v8h b = *(const v8h*)&sB[(ct * 16 + m16) * 136 + ks * 32 + quad * 8];
            c[ct] = __builtin_amdgcn_mfma_f32_16x16x32_f16(a, b, c[ct], 0, 0, 0);
        }
    }

#pragma unroll
    for (int r = 0; r < 4; ++r) {
        const int row = tile0 + w * 16 + quad * 4 + r;
        if (row < n_nodes) {
            const float inm = inorm[row];
            const float osc = LAST ? 1.0f : onorm[row];
#pragma unroll
            for (int ct = 0; ct < 8; ++ct) {
                const int col = ct * 16 + m16;
                float v = fmaf(c[ct][r], inm, bias[col]);
                if (!LAST) {
                    v = fmaxf(v, 0.f) * osc;
                    ((__half*)outv)[(size_t)row * D + col] = __float2half(v);
                } else {
                    ((float*)outv)[(size_t)row * D + col] = v;
                }
            }
        }
    }
}

// ---------------------------------------------------------------------------
// Host launch
// ---------------------------------------------------------------------------
extern "C" void kernel_launch(void* const* d_in, const int* in_sizes, int n_in,
                              void* d_out, int out_size, void* d_ws, size_t ws_size,
                              hipStream_t stream) {
    const float* x   = (const float*)d_in[0];
    const int*   src = (const int*)d_in[1];
    const int*   dst = (const int*)d_in[2];
    const float* W1  = (const float*)d_in[3];
    const float* b1  = (const float*)d_in[4];
    const float* W2  = (const float*)d_in[5];
    const float* b2  = (const float*)d_in[6];
    const float* W3  = (const float*)d_in[7];
    const float* b3  = (const float*)d_in[8];

    const int N = in_sizes[0] / D;   // 50000
    const int E = in_sizes[1];       // 800000

    char* p = (char*)d_ws;
    auto alloc = [&](size_t bytes) -> void* {
        void* r = (void*)p;
        p += (bytes + 255) & ~(size_t)255;
        return r;
    };
    int*           cnt_out = (int*)alloc((size_t)N * 4);
    int*           cnt_in  = (int*)alloc((size_t)N * 4);
    int*           rp      = (int*)alloc((size_t)(N + 1) * 4);
    int*           bsum    = (int*)alloc(1024 * 4);
    float*         onorm   = (float*)alloc((size_t)N * 4);
    float*         inorm   = (float*)alloc((size_t)N * 4);
    int*           srcs    = (int*)alloc((size_t)E * 4);
    unsigned char* lrank   = (unsigned char*)alloc((size_t)E);
    _Float16*      wt      = (_Float16*)alloc((size_t)3 * D * D * 2);
    __half*        hbuf0   = (__half*)alloc((size_t)N * D * 2);  // y1, then h2
    __half*        hbuf1   = (__half*)alloc((size_t)N * D * 2);  // h1
    char*          scratch = (char*)alloc((size_t)3 * HB * ((N + 3) / 4) * 4);  // 19.2MB

    const int W = (N + 3) / 4;              // 12500 packed histogram words
    const int epb = (E + HB - 1) / HB;      // 6250 edges per histogram block
    unsigned* partial_in  = (unsigned*)scratch;
    unsigned* partial_out = partial_in + (size_t)HB * W;
    unsigned* offs_in     = partial_out + (size_t)HB * W;
    float*    outf        = (float*)d_out;

    const int nb = (N + 1023) / 1024;       // 49
    const int nbW = (W + 255) / 256;        // 49
    const int gemmGrid = (N + 127) / 128;   // 391
    const int fillGrid = (E + 1023) / 1024; // 782
    const int aggGrid = (N + 3) / 4;        // 12500
    const int fuseGrid = (N + 63) / 64;     // 782

    // Graph build (hist + W-prep merged); no global atomics, no memset
    hist_kernel<<<2 * HB + 3, HT, 0, stream>>>(src, dst, partial_out, partial_in, lrank,
                                               W1, W2, W3, wt, E, W, epb);
    reduce_hist_kernel<<<2 * nbW, 256, 0, stream>>>(partial_out, partial_in, offs_in,
                                                    cnt_out, cnt_in, W, N, nbW);
    scan_block_kernel<<<nb, 1024, 0, stream>>>(cnt_in, rp, bsum, N);
    finalize_kernel<<<nb, 1024, 0, stream>>>(rp, bsum, cnt_out, cnt_in, onorm, inorm, N, nb, E);

    // Fused: GEMM1 (y1 = (x@W1)*onorm -> fp16) + CSR fill
    gemm1_fill_kernel<<<gemmGrid + fillGrid, 1024, 0, stream>>>(
        x, wt, onorm, hbuf0, N,
        src, dst, lrank, offs_in, rp, srcs, E, epb, W, gemmGrid);

    // Layer 1 aggregate + full epilogue -> h1 fp16
    aggregate_kernel<<<aggGrid, 256, 0, stream>>>(
        hbuf0, onorm, inorm, b1, rp, srcs, hbuf1, N);
    // Layer 2 fused: h2 = relu((agg(h1)@W2)*inorm+b2)*onorm -> fp16
    agg_gemm_kernel<false><<<fuseGrid, 256, 0, stream>>>(
        hbuf1, wt + (size_t)D * D, b2, inorm, onorm, rp, srcs, hbuf0, N);
    // Layer 3 fused: out = (agg(h2)@W3)*inorm+b3 -> fp32 d_out
    agg_gemm_kernel<true><<<fuseGrid, 256, 0, stream>>>(
        hbuf0, wt + (size_t)2 * D * D, b3, inorm, onorm, rp, srcs, outf, N);
}

// Round 14
// 243.818 us; speedup vs baseline: 1.3354x; 1.3354x over previous
//
#include <hip/hip_runtime.h>
#include <hip/hip_fp16.h>

#define D 128
#define HB 128        // histogram blocks per role (edge-partitioned)
#define HT 1024       // threads per histogram block
#define WMAX 12800    // LDS histogram words (4 nodes/word, byte counters)

struct alignas(16) H8 { __half2 h[4]; };
typedef _Float16 v8h __attribute__((ext_vector_type(8)));
typedef float v4f __attribute__((ext_vector_type(4)));

// ---------------------------------------------------------------------------
// Edge-partitioned LDS histogram (R8-proven) + merged W-prep role (3 tail
// blocks transpose W1/2/3 to fp16 [n][k] for MFMA B-frags).
// Block b histograms its own 6250-edge slice into byte-packed LDS counters;
// dst role captures local rank from ds_add_rtn.
// ---------------------------------------------------------------------------
__global__ __launch_bounds__(HT) void hist_kernel(const int* __restrict__ src,
                                                  const int* __restrict__ dst,
                                                  unsigned* __restrict__ partial_out,
                                                  unsigned* __restrict__ partial_in,
                                                  unsigned char* __restrict__ lrank,
                                                  const float* __restrict__ W1,
                                                  const float* __restrict__ W2,
                                                  const float* __restrict__ W3,
                                                  _Float16* __restrict__ wt,
                                                  int nE, int W, int epb) {
    const int t = threadIdx.x;
    if ((int)blockIdx.x >= 2 * HB) {                 // W-prep role
        const int l = blockIdx.x - 2 * HB;
        const float* Wsrc = (l == 0) ? W1 : ((l == 1) ? W2 : W3);
        _Float16* o = wt + (size_t)l * D * D;
        for (int i = t; i < D * D; i += HT) {
            const int k = i >> 7, n = i & 127;
            o[n * D + k] = (_Float16)Wsrc[i];
        }
        return;
    }
    __shared__ unsigned lcnt[WMAX];
    const bool is_dst = (blockIdx.x < HB);
    const int b = is_dst ? blockIdx.x : (blockIdx.x - HB);
    for (int i = t; i < W; i += HT) lcnt[i] = 0;
    __syncthreads();
    const int e0 = b * epb;
    const int e1 = min(nE, e0 + epb);
    if (is_dst) {
        for (int e = e0 + t; e < e1; e += HT) {
            const int d = dst[e];
            const unsigned sh = (unsigned)(d & 3) * 8u;
            const unsigned old = atomicAdd(&lcnt[d >> 2], 1u << sh);
            lrank[e] = (unsigned char)((old >> sh) & 0xffu);
        }
    } else {
        for (int e = e0 + t; e < e1; e += HT) {
            const int s = src[e];
            atomicAdd(&lcnt[s >> 2], 1u << ((unsigned)(s & 3) * 8u));
        }
    }
    __syncthreads();
    unsigned* g = (is_dst ? partial_in : partial_out) + (size_t)b * W;
    for (int i = t; i < W; i += HT) g[i] = lcnt[i];
}

// ---------------------------------------------------------------------------
// Reduce 128 partials per node-word (byte-parallel; totals < 256).
// ---------------------------------------------------------------------------
__global__ __launch_bounds__(256) void reduce_hist_kernel(const unsigned* __restrict__ partial_out,
                                                          const unsigned* __restrict__ partial_in,
                                                          unsigned* __restrict__ offs_in,
                                                          int* __restrict__ cnt_out,
                                                          int* __restrict__ cnt_in,
                                                          int W, int n, int nbW) {
    const bool is_dst = ((int)blockIdx.x < nbW);
    const int w = (is_dst ? blockIdx.x : (blockIdx.x - nbW)) * 256 + threadIdx.x;
    if (w >= W) return;
    unsigned run = 0;
    if (is_dst) {
#pragma unroll 16
        for (int b = 0; b < HB; ++b) {
            const unsigned c = partial_in[(size_t)b * W + w];
            offs_in[(size_t)b * W + w] = run;
            run += c;
        }
    } else {
#pragma unroll 16
        for (int b = 0; b < HB; ++b) run += partial_out[(size_t)b * W + w];
    }
    int* cnt = is_dst ? cnt_in : cnt_out;
    const int n0 = w * 4;
    const int4 c4 = make_int4((int)(run & 0xffu), (int)((run >> 8) & 0xffu),
                              (int)((run >> 16) & 0xffu), (int)((run >> 24) & 0xffu));
    if (n0 + 3 < n) {
        *(int4*)&cnt[n0] = c4;
    } else {
        const int* cp = &c4.x;
        for (int i = 0; i < 4 && n0 + i < n; ++i) cnt[n0 + i] = cp[i];
    }
}

// ---------------------------------------------------------------------------
// Exclusive scan stage 1.
// ---------------------------------------------------------------------------
__global__ __launch_bounds__(1024) void scan_block_kernel(const int* __restrict__ deg,
                                                          int* __restrict__ rp,
                                                          int* __restrict__ bsum, int n) {
    __shared__ int wsum[16];
    const int t = threadIdx.x;
    const int lane = t & 63;
    const int wid = t >> 6;
    const int i = blockIdx.x * 1024 + t;
    const int v = (i < n) ? deg[i] : 0;
    int s = v;
#pragma unroll
    for (int off = 1; off < 64; off <<= 1) {
        int u = __shfl_up(s, off, 64);
        if (lane >= off) s += u;
    }
    if (lane == 63) wsum[wid] = s;
    __syncthreads();
    if (wid == 0) {
        int ws = (lane < 16) ? wsum[lane] : 0;
#pragma unroll
        for (int off = 1; off < 16; off <<= 1) {
            int u = __shfl_up(ws, off, 64);
            if (lane >= off) ws += u;
        }
        if (lane < 16) wsum[lane] = ws;
    }
    __syncthreads();
    const int excl = s - v + ((wid > 0) ? wsum[wid - 1] : 0);
    if (i < n) rp[i] = excl;
    if (t == 0) bsum[blockIdx.x] = wsum[15];
}

// ---------------------------------------------------------------------------
// Stage 2 fused with norms; rp[n]=E known a priori.
// ---------------------------------------------------------------------------
__global__ __launch_bounds__(1024) void finalize_kernel(int* __restrict__ rp,
                                                        const int* __restrict__ bsum,
                                                        const int* __restrict__ cnt_out,
                                                        const int* __restrict__ cnt_in,
                                                        float* __restrict__ onorm,
                                                        float* __restrict__ inorm,
                                                        int n, int nb, int nE) {
    __shared__ int prefix_s;
    const int t = threadIdx.x;
    if (t < 64) {
        int v = (t < nb && t < (int)blockIdx.x) ? bsum[t] : 0;
#pragma unroll
        for (int off = 1; off < 64; off <<= 1) v += __shfl_xor(v, off, 64);
        if (t == 0) prefix_s = v;
    }
    __syncthreads();
    const int i = blockIdx.x * 1024 + t;
    if (i < n) {
        rp[i] += prefix_s;
        onorm[i] = rsqrtf(fmaxf((float)cnt_out[i], 1.0f));
        inorm[i] = rsqrtf(fmaxf((float)cnt_in[i], 1.0f));
    }
    if (blockIdx.x == 0 && t == 0) rp[n] = nE;
}

// ---------------------------------------------------------------------------
// FUSED: GEMM1 (y1 = (x@W1)*onorm -> fp16, MFMA) + atomic-free CSR fill.
// R12-proven: independent work, disjoint resources, and crucially the fill
// blocks carry NO LDS so they keep full wave residency (the R13 agg+gemm
// fusion failed precisely by violating this — 52KB LDS cut the gather's
// waves/CU from 32 to 12 and throughput fell proportionally).
// ---------------------------------------------------------------------------
__global__ __launch_bounds__(1024) void gemm1_fill_kernel(
    const float* __restrict__ x, const _Float16* __restrict__ wt,
    const float* __restrict__ onorm, __half* __restrict__ y1, int nrows,
    const int* __restrict__ src, const int* __restrict__ dst,
    const unsigned char* __restrict__ lrank, const unsigned* __restrict__ offs_in,
    const int* __restrict__ rp, int* __restrict__ srcs_sorted,
    int nE, int epb, int W, int nGemmBlocks) {
    __shared__ _Float16 sA[128 * 136];
    __shared__ _Float16 sB[128 * 136];
    const int t = threadIdx.x;

    if ((int)blockIdx.x >= nGemmBlocks) {
        // ---- fill role: one edge per thread ----
        const int e = (blockIdx.x - nGemmBlocks) * 1024 + t;
        if (e < nE) {
            const int d = dst[e];
            const int b = e / epb;
            const unsigned off =
                (offs_in[(size_t)b * W + (d >> 2)] >> ((unsigned)(d & 3) * 8u)) & 0xffu;
            srcs_sorted[rp[d] + (int)off + (int)lrank[e]] = src[e];
        }
        return;
    }

    // ---- GEMM role: 128x128 tile, 16 waves ----
    const int row0 = blockIdx.x * 128;
    const int rr = t >> 4;      // 64 staging rows per pass
    const int c8 = t & 15;
#pragma unroll
    for (int pass = 0; pass < 2; ++pass) {
        const int row = pass * 64 + rr;
        *(float4*)&sB[row * 136 + c8 * 8] = *(const float4*)&wt[(size_t)row * D + c8 * 8];
        const int grow = row0 + row;
        float4 u0 = make_float4(0.f, 0.f, 0.f, 0.f);
        float4 u1 = u0;
        if (grow < nrows) {
            const float* ap = x + (size_t)grow * D + c8 * 8;
            u0 = ((const float4*)ap)[0];
            u1 = ((const float4*)ap)[1];
        }
        v8h hv;
        hv[0] = (_Float16)u0.x; hv[1] = (_Float16)u0.y;
        hv[2] = (_Float16)u0.z; hv[3] = (_Float16)u0.w;
        hv[4] = (_Float16)u1.x; hv[5] = (_Float16)u1.y;
        hv[6] = (_Float16)u1.z; hv[7] = (_Float16)u1.w;
        *(v8h*)&sA[row * 136 + c8 * 8] = hv;
    }
    __syncthreads();

    const int w = t >> 6;       // 16 waves
    const int lane = t & 63;
    const int m16 = lane & 15;
    const int quad = lane >> 4;
    const int rt = w >> 1;      // row-tile 0..7
    const int ch = w & 1;       // col half 0..1

    v4f c[4];
#pragma unroll
    for (int ct = 0; ct < 4; ++ct) c[ct] = (v4f){0.f, 0.f, 0.f, 0.f};

#pragma unroll
    for (int ks = 0; ks < 4; ++ks) {
        const v8h a = *(const v8h*)&sA[(rt * 16 + m16) * 136 + ks * 32 + quad * 8];
#pragma unroll
        for (int ct = 0; ct < 4; ++ct) {
            const v8h b = *(const v8h*)&sB[((ch * 4 + ct) * 16 + m16) * 136 + ks * 32 + quad * 8];
            c[ct] = __builtin_amdgcn_mfma_f32_16x16x32_f16(a, b, c[ct], 0, 0, 0);
        }
    }

#pragma unroll
    for (int r = 0; r < 4; ++r) {
        const int row = row0 + rt * 16 + quad * 4 + r;
        if (row < nrows) {
            const float osc = onorm[row];
#pragma unroll
            for (int ct = 0; ct < 4; ++ct) {
                const int col = (ch * 4 + ct) * 16 + m16;
                y1[(size_t)row * D + col] = __float2half(c[ct][r] * osc);
            }
        }
    }
}

// ---------------------------------------------------------------------------
// Aggregation, wave-per-node, WIDE fp16 gather (R11-proven: 4 rows per load
// instruction, 4KB in flight per wave, no LDS -> full 32 waves/CU residency;
// fabric-throughput-bound at ~4.4TB/s — the measured floor after R5/R7/R10/
// R13 all failed to beat it). Inputs onorm-prescaled; fp16 out.
// EPI (layer 1): relu(r*inorm+b)*onorm.
// ---------------------------------------------------------------------------
template <bool EPI>
__global__ __launch_bounds__(256) void aggregate_kernel(const __half* __restrict__ xh,
                                                        const float* __restrict__ onorm,
                                                        const float* __restrict__ inorm,
                                                        const float* __restrict__ bias,
                                                        const int* __restrict__ rp,
                                                        const int* __restrict__ srcs,
                                                        __half* __restrict__ agg, int n_nodes) {
    const int node = blockIdx.x * 4 + (threadIdx.x >> 6);
    const int lane = threadIdx.x & 63;
    const int rg = lane >> 4;       // edge slot 0..3
    const int c8 = lane & 15;       // 16B chunk within the 256B row
    if (node >= n_nodes) return;
    const int e0 = rp[node];
    const int e1 = rp[node + 1];

    float acc0[8], acc1[8];
#pragma unroll
    for (int j = 0; j < 8; ++j) { acc0[j] = 0.f; acc1[j] = 0.f; }

    auto accum = [&](float* acc, const H8 v) {
#pragma unroll
        for (int j = 0; j < 4; ++j) {
            acc[2 * j]     += __low2float(v.h[j]);
            acc[2 * j + 1] += __high2float(v.h[j]);
        }
    };

    int e = e0;
    for (; e + 16 <= e1; e += 16) {
        const int s0 = srcs[e + rg];
        const int s1 = srcs[e + 4 + rg];
        const int s2 = srcs[e + 8 + rg];
        const int s3 = srcs[e + 12 + rg];
        const H8 v0 = ((const H8*)(xh + (size_t)s0 * D))[c8];
        const H8 v1 = ((const H8*)(xh + (size_t)s1 * D))[c8];
        const H8 v2 = ((const H8*)(xh + (size_t)s2 * D))[c8];
        const H8 v3 = ((const H8*)(xh + (size_t)s3 * D))[c8];
        accum(acc0, v0); accum(acc1, v1); accum(acc0, v2); accum(acc1, v3);
    }
    for (; e + 4 <= e1; e += 4) {
        const int s0 = srcs[e + rg];
        accum(acc0, ((const H8*)(xh + (size_t)s0 * D))[c8]);
    }
    if (e < e1 && rg < (e1 - e)) {
        const int s0 = srcs[e + rg];
        accum(acc1, ((const H8*)(xh + (size_t)s0 * D))[c8]);
    }

    float r[8];
#pragma unroll
    for (int j = 0; j < 8; ++j) r[j] = acc0[j] + acc1[j];
#pragma unroll
    for (int off = 16; off < 64; off <<= 1)
#pragma unroll
        for (int j = 0; j < 8; ++j) r[j] += __shfl_xor(r[j], off, 64);

    if (rg == 0) {
        if (EPI) {
            const float inm = inorm[node];
            const float onm = onorm[node];
            const float4 bv0 = ((const float4*)bias)[c8 * 2];
            const float4 bv1 = ((const float4*)bias)[c8 * 2 + 1];
            const float* bp0 = &bv0.x;
            const float* bp1 = &bv1.x;
#pragma unroll
            for (int j = 0; j < 4; ++j) {
                r[j]     = fmaxf(fmaf(r[j],     inm, bp0[j]), 0.f) * onm;
                r[j + 4] = fmaxf(fmaf(r[j + 4], inm, bp1[j]), 0.f) * onm;
            }
        }
        H8 h;
#pragma unroll
        for (int j = 0; j < 4; ++j) h.h[j] = __floats2half2_rn(r[2 * j], r[2 * j + 1]);
        ((H8*)(agg + (size_t)node * D))[c8] = h;
    }
}

// ---------------------------------------------------------------------------
// MFMA GEMM for layers 2/3 (R9-proven). 128x128 tile, fp16 operands, fp32
// acc. LDS stride 136 halves. Epilogue: FULL(*inorm+bias), RELU, OSCALE,
// OUT16. A is fp16 row-major.
// ---------------------------------------------------------------------------
template <bool FULL, bool RELU, bool OSCALE, bool OUT16>
__global__ __launch_bounds__(256) void gemm_mfma_kernel(const __half* __restrict__ Ah,
                                                        const _Float16* __restrict__ Wt,
                                                        const float* __restrict__ bias,
                                                        const float* __restrict__ inorm,
                                                        const float* __restrict__ onorm,
                                                        void* __restrict__ outv, int nrows) {
    __shared__ _Float16 sA[128 * 136];
    __shared__ _Float16 sB[128 * 136];
    const int t = threadIdx.x;
    const int row0 = blockIdx.x * 128;
    const int rr = t >> 4;
    const int c8 = t & 15;

#pragma unroll
    for (int pass = 0; pass < 8; ++pass) {
        const int row = pass * 16 + rr;
        *(float4*)&sB[row * 136 + c8 * 8] = *(const float4*)&Wt[(size_t)row * D + c8 * 8];
        const int grow = row0 + row;
        float4 v = make_float4(0.f, 0.f, 0.f, 0.f);
        if (grow < nrows)
            v = *(const float4*)((const _Float16*)Ah + (size_t)grow * D + c8 * 8);
        *(float4*)&sA[row * 136 + c8 * 8] = v;
    }
    __syncthreads();

    const int w = t >> 6;
    const int lane = t & 63;
    const int m16 = lane & 15;
    const int quad = lane >> 4;

    v4f c[2][8];
#pragma unroll
    for (int rt = 0; rt < 2; ++rt)
#pragma unroll
        for (int ct = 0; ct < 8; ++ct) c[rt][ct] = (v4f){0.f, 0.f, 0.f, 0.f};

#pragma unroll
    for (int ks = 0; ks < 4; ++ks) {
        v8h afr[2], bfr[8];
#pragma unroll
        for (int rt = 0; rt < 2; ++rt)
            afr[rt] = *(const v8h*)&sA[(w * 32 + rt * 16 + m16) * 136 + ks * 32 + quad * 8];
#pragma unroll
        for (int ct = 0; ct < 8; ++ct)
            bfr[ct] = *(const v8h*)&sB[(ct * 16 + m16) * 136 + ks * 32 + quad * 8];
#pragma unroll
        for (int rt = 0; rt < 2; ++rt)
#pragma unroll
            for (int ct = 0; ct < 8; ++ct)
                c[rt][ct] = __builtin_amdgcn_mfma_f32_16x16x32_f16(afr[rt], bfr[ct], c[rt][ct], 0, 0, 0);
    }

#pragma unroll
    for (int rt = 0; rt < 2; ++rt) {
#pragma unroll
        for (int r = 0; r < 4; ++r) {
            const int row = row0 + w * 32 + rt * 16 + quad * 4 + r;
            if (row < nrows) {
                const float inm = FULL ? inorm[row] : 1.0f;
                const float osc = OSCALE ? onorm[row] : 1.0f;
#pragma unroll
                for (int ct = 0; ct < 8; ++ct) {
                    const int col = ct * 16 + m16;
                    float v = c[rt][ct][r];
                    if (FULL) v = fmaf(v, inm, bias[col]);
                    if (RELU) v = fmaxf(v, 0.f);
                    if (OSCALE) v *= osc;
                    if (OUT16) ((__half*)outv)[(size_t)row * D + col] = __float2half(v);
                    else       ((float*)outv)[(size_t)row * D + col] = v;
                }
            }
        }
    }
}

// ---------------------------------------------------------------------------
// Host launch
// ---------------------------------------------------------------------------
extern "C" void kernel_launch(void* const* d_in, const int* in_sizes, int n_in,
                              void* d_out, int out_size, void* d_ws, size_t ws_size,
                              hipStream_t stream) {
    const float* x   = (const float*)d_in[0];
    const int*   src = (const int*)d_in[1];
    const int*   dst = (const int*)d_in[2];
    const float* W1  = (const float*)d_in[3];
    const float* b1  = (const float*)d_in[4];
    const float* W2  = (const float*)d_in[5];
    const float* b2  = (const float*)d_in[6];
    const float* W3  = (const float*)d_in[7];
    const float* b3  = (const float*)d_in[8];

    const int N = in_sizes[0] / D;   // 50000
    const int E = in_sizes[1];       // 800000

    char* p = (char*)d_ws;
    auto alloc = [&](size_t bytes) -> void* {
        void* r = (void*)p;
        p += (bytes + 255) & ~(size_t)255;
        return r;
    };
    int*           cnt_out = (int*)alloc((size_t)N * 4);
    int*           cnt_in  = (int*)alloc((size_t)N * 4);
    int*           rp      = (int*)alloc((size_t)(N + 1) * 4);
    int*           bsum    = (int*)alloc(1024 * 4);
    float*         onorm   = (float*)alloc((size_t)N * 4);
    float*         inorm   = (float*)alloc((size_t)N * 4);
    int*           srcs    = (int*)alloc((size_t)E * 4);
    unsigned char* lrank   = (unsigned char*)alloc((size_t)E);
    _Float16*      wt      = (_Float16*)alloc((size_t)3 * D * D * 2);
    __half*        hbuf0   = (__half*)alloc((size_t)N * D * 2);  // y1, then h2
    __half*        hbuf1   = (__half*)alloc((size_t)N * D * 2);  // h1
    char*          scratch = (char*)alloc((size_t)3 * HB * ((N + 3) / 4) * 4);  // 19.2MB

    const int W = (N + 3) / 4;              // 12500 packed histogram words
    const int epb = (E + HB - 1) / HB;      // 6250 edges per histogram block
    unsigned* partial_in  = (unsigned*)scratch;
    unsigned* partial_out = partial_in + (size_t)HB * W;
    unsigned* offs_in     = partial_out + (size_t)HB * W;
    __half*   abuf        = (__half*)scratch;                  // a2, a3 (fp16)
    float*    outf        = (float*)d_out;

    const int nb = (N + 1023) / 1024;       // 49
    const int nbW = (W + 255) / 256;        // 49
    const int gemmGrid = (N + 127) / 128;   // 391
    const int fillGrid = (E + 1023) / 1024; // 782
    const int aggGrid = (N + 3) / 4;        // 12500

    // Graph build (hist + W-prep merged); no global atomics, no memset
    hist_kernel<<<2 * HB + 3, HT, 0, stream>>>(src, dst, partial_out, partial_in, lrank,
                                               W1, W2, W3, wt, E, W, epb);
    reduce_hist_kernel<<<2 * nbW, 256, 0, stream>>>(partial_out, partial_in, offs_in,
                                                    cnt_out, cnt_in, W, N, nbW);
    scan_block_kernel<<<nb, 1024, 0, stream>>>(cnt_in, rp, bsum, N);
    finalize_kernel<<<nb, 1024, 0, stream>>>(rp, bsum, cnt_out, cnt_in, onorm, inorm, N, nb, E);

    // Fused: GEMM1 (y1 = (x@W1)*onorm -> fp16) + CSR fill (independent work)
    gemm1_fill_kernel<<<gemmGrid + fillGrid, 1024, 0, stream>>>(
        x, wt, onorm, hbuf0, N,
        src, dst, lrank, offs_in, rp, srcs, E, epb, W, gemmGrid);

    // Layer 1 aggregate + full epilogue -> h1 fp16
    aggregate_kernel<true><<<aggGrid, 256, 0, stream>>>(
        hbuf0, onorm, inorm, b1, rp, srcs, hbuf1, N);
    // Layer 2: a2 = agg(h1) fp16; h2 = relu((a2@W2)*inorm+b2)*onorm -> fp16
    aggregate_kernel<false><<<aggGrid, 256, 0, stream>>>(
        hbuf1, onorm, inorm, b2, rp, srcs, abuf, N);
    gemm_mfma_kernel<true, true, true, true><<<gemmGrid, 256, 0, stream>>>(
        abuf, wt + (size_t)D * D, b2, inorm, onorm, hbuf0, N);
    // Layer 3: a3 = agg(h2) fp16; out = (a3@W3)*inorm+b3 -> fp32 d_out
    aggregate_kernel<false><<<aggGrid, 256, 0, stream>>>(
        hbuf0, onorm, inorm, b3, rp, srcs, abuf, N);
    gemm_mfma_kernel<true, false, false, false><<<gemmGrid, 256, 0, stream>>>(
        abuf, wt + (size_t)2 * D * D, b3, inorm, onorm, outf, N);
}